// Round 3
// baseline (668.233 us; speedup 1.0000x reference)
//
#include <hip/hip_runtime.h>
#include <hip/hip_bf16.h>

typedef __hip_bfloat16 bf16;
typedef __attribute__((ext_vector_type(8))) short short8;
typedef __attribute__((ext_vector_type(4))) float f32x4;

__device__ __forceinline__ float bfu(unsigned short b) {
    unsigned u = ((unsigned)b) << 16;
    float f;
    __builtin_memcpy(&f, &u, 4);
    return f;
}
__device__ __forceinline__ unsigned short f2b(float f) {
    return (unsigned short)(__hip_bfloat16_raw(__float2bfloat16(f)).x);
}

// async global->LDS, 16B per lane; lds dest must be wave-uniform base.
__device__ __forceinline__ void gl_lds16(const void* g, void* l) {
    __builtin_amdgcn_global_load_lds(
        (const __attribute__((address_space(1))) void*)g,
        (__attribute__((address_space(3))) void*)l, 16, 0, 0);
}

// ---------------------------------------------------------------------------
// Threefry-2x32 (20 rounds), JAX partitionable: keep = top bit of (x0^x1)==0
// ---------------------------------------------------------------------------
__device__ __forceinline__ bool keep_elem(unsigned idx) {
    const unsigned k0 = 0u, k1 = 42u;
    const unsigned k2 = k0 ^ k1 ^ 0x1BD11BDAu;
    unsigned x0 = k0;
    unsigned x1 = idx + k1;
#define TF_QR(R) { x0 += x1; x1 = (x1 << R) | (x1 >> (32 - R)); x1 ^= x0; }
    TF_QR(13) TF_QR(15) TF_QR(26) TF_QR(6)
    x0 += k1; x1 += k2 + 1u;
    TF_QR(17) TF_QR(29) TF_QR(16) TF_QR(24)
    x0 += k2; x1 += k0 + 2u;
    TF_QR(13) TF_QR(15) TF_QR(26) TF_QR(6)
    x0 += k0; x1 += k1 + 3u;
    TF_QR(17) TF_QR(29) TF_QR(16) TF_QR(24)
    x0 += k1; x1 += k2 + 4u;
    TF_QR(13) TF_QR(15) TF_QR(26) TF_QR(6)
    x0 += k2; x1 += k0 + 5u;
#undef TF_QR
    return (((x0 ^ x1) >> 31) & 1u) == 0u;
}

// ---------------------------------------------------------------------------
// Merged dtype detection: flag[0] edges int64?, flag[1] x f32?, flag[2] W f32?
// ---------------------------------------------------------------------------
__global__ void detect_all_k(const unsigned* __restrict__ ei,
                             const unsigned short* __restrict__ x,
                             const unsigned short* __restrict__ w1,
                             int* __restrict__ flag) {
    __shared__ int red[256];
    if (blockIdx.x == 0) {
        unsigned v = 0;
        for (int i = threadIdx.x; i < 2048; i += 256) v |= ei[2 * i + 1];
        red[threadIdx.x] = (int)v;
        __syncthreads();
        for (int s = 128; s > 0; s >>= 1) {
            if (threadIdx.x < s) red[threadIdx.x] |= red[threadIdx.x + s];
            __syncthreads();
        }
        if (threadIdx.x == 0) flag[0] = (red[0] == 0) ? 1 : 0;
    } else {
        const unsigned short* p = (blockIdx.x == 1) ? x : w1;
        int cnt = 0;
        for (int i = threadIdx.x; i < 1024; i += 256) {
            unsigned short b = p[2 * i];
            int e = (b >> 7) & 0xFF;
            if ((b & 0x7FFF) == 0 || (e >= 100 && e < 140)) cnt++;
        }
        red[threadIdx.x] = cnt;
        __syncthreads();
        for (int s = 128; s > 0; s >>= 1) {
            if (threadIdx.x < s) red[threadIdx.x] += red[threadIdx.x + s];
            __syncthreads();
        }
        if (threadIdx.x == 0) flag[blockIdx.x] = (red[0] < 614) ? 1 : 0;
    }
}

__global__ void convert_edges_k(const void* __restrict__ src, int* __restrict__ out,
                                int twoE, const int* __restrict__ flag) {
    int i = blockIdx.x * 256 + threadIdx.x;
    if (i >= twoE) return;
    if (flag[0]) out[i] = (int)((const unsigned long long*)src)[i];
    else         out[i] = ((const int*)src)[i];
}

// canonicalize + transpose weight [K,Nn] -> [Nn,K] (both multiples of 16)
__global__ void canon_transpose_k(const void* __restrict__ src, unsigned short* __restrict__ dst,
                                  int K, int Nn, const int* __restrict__ flag, int fidx) {
    __shared__ unsigned short tile[16][17];
    int k0 = blockIdx.x * 16, n0 = blockIdx.y * 16;
    int k = k0 + threadIdx.y, n = n0 + threadIdx.x;
    unsigned short v;
    if (flag[fidx]) v = f2b(((const float*)src)[(size_t)k * Nn + n]);
    else            v = ((const unsigned short*)src)[(size_t)k * Nn + n];
    tile[threadIdx.y][threadIdx.x] = v;
    __syncthreads();
    int nn = n0 + threadIdx.y, kk = k0 + threadIdx.x;
    dst[(size_t)nn * K + kk] = tile[threadIdx.x][threadIdx.y];
}

// merged bias canon: b1c[0..H) from b1, bcat[0..DOUT) from bmu, [DOUT..2*DOUT) from bls
__global__ void canon_bias_k(const void* __restrict__ b1, const void* __restrict__ bmu,
                             const void* __restrict__ bls, bf16* __restrict__ b1c,
                             bf16* __restrict__ bcat, int H, int DOUT,
                             const int* __restrict__ flag) {
    int i = blockIdx.x * 256 + threadIdx.x;
    int f = flag[2];
    if (i < H) {
        b1c[i] = f ? __float2bfloat16(((const float*)b1)[i]) : ((const bf16*)b1)[i];
    } else if (i < H + DOUT) {
        int j = i - H;
        bcat[j] = f ? __float2bfloat16(((const float*)bmu)[j]) : ((const bf16*)bmu)[j];
    } else if (i < H + 2 * DOUT) {
        int j = i - H - DOUT;
        bcat[DOUT + j] = f ? __float2bfloat16(((const float*)bls)[j]) : ((const bf16*)bls)[j];
    }
}

// ---------------------------------------------------------------------------
// CSR build
// ---------------------------------------------------------------------------
__global__ void zero_int_k(int* __restrict__ p, int n) {
    int i = blockIdx.x * 256 + threadIdx.x;
    if (i < n) p[i] = 0;
}
__global__ void deg_count_k(const int* __restrict__ edges, int* __restrict__ degi,
                            int E, int n) {
    int e = blockIdx.x * 256 + threadIdx.x;
    if (e >= E) return;
    int d = edges[E + e];
    d = (d < 0) ? 0 : (d >= n ? n - 1 : d);
    atomicAdd(&degi[d], 1);
}
__global__ void block_sums_k(const int* __restrict__ deg, int* __restrict__ partial, int n) {
    __shared__ int sh[256];
    int i = blockIdx.x * 256 + threadIdx.x;
    sh[threadIdx.x] = (i < n) ? deg[i] : 0;
    __syncthreads();
    for (int s = 128; s > 0; s >>= 1) {
        if (threadIdx.x < s) sh[threadIdx.x] += sh[threadIdx.x + s];
        __syncthreads();
    }
    if (threadIdx.x == 0) partial[blockIdx.x] = sh[0];
}
__global__ void scan_partials_k(int* __restrict__ partial, int G) {
    __shared__ int sh[256];
    int v = (threadIdx.x < G) ? partial[threadIdx.x] : 0;
    sh[threadIdx.x] = v;
    __syncthreads();
    for (int s = 1; s < 256; s <<= 1) {
        int t = 0;
        if (threadIdx.x >= s) t = sh[threadIdx.x - s];
        __syncthreads();
        sh[threadIdx.x] += t;
        __syncthreads();
    }
    if (threadIdx.x < G) partial[threadIdx.x] = sh[threadIdx.x] - v;
}
// scan + dinv fused (dinv[i] = rsqrt(1+deg[i]))
__global__ void scan_block_k(const int* __restrict__ deg, const int* __restrict__ partial,
                             int* __restrict__ row_ptr, float* __restrict__ dinv, int n) {
    __shared__ int sh[256];
    int i = blockIdx.x * 256 + threadIdx.x;
    int v = (i < n) ? deg[i] : 0;
    sh[threadIdx.x] = v;
    __syncthreads();
    for (int s = 1; s < 256; s <<= 1) {
        int t = 0;
        if (threadIdx.x >= s) t = sh[threadIdx.x - s];
        __syncthreads();
        sh[threadIdx.x] += t;
        __syncthreads();
    }
    int incl = sh[threadIdx.x];
    int base = partial[blockIdx.x];
    if (i < n) {
        row_ptr[i] = base + incl - v;
        dinv[i] = rsqrtf(1.0f + (float)v);
    }
    if (i == n - 1) row_ptr[n] = base + incl;
}
__global__ void fill_k(const int* __restrict__ edges, const int* __restrict__ row_ptr,
                       int* __restrict__ cnt, int* __restrict__ col, int E, int n) {
    int e = blockIdx.x * 256 + threadIdx.x;
    if (e >= E) return;
    int s = edges[e], d = edges[E + e];
    s = (s < 0) ? 0 : (s >= n ? n - 1 : s);
    d = (d < 0) ? 0 : (d >= n ? n - 1 : d);
    int pos = row_ptr[d] + atomicAdd(&cnt[d], 1);
    col[pos] = s;
}

// ---------------------------------------------------------------------------
// Wide-N MFMA GEMM: C[M,512] = A[M,K] @ Bt[512,K]^T, BM=128, BN=512, BK=32.
// 8 waves (2M x 4N), each wave 4x8 of 16x16x32 bf16 MFMA. A read exactly once.
// drop=1: A-tile staged via registers from x (f32/bf16 per flag[1]) with
//         fused threefry dropout (idx = row*K + k, matches reference mask).
// drop=0: A is bf16, staged via global_load_lds.
// Epilogue: Cb!=null -> bf16 [M,512]; else f32 split: cols<256 -> Cf,
//           cols>=256 -> Cf2 (row stride 256), + bf16 bias (512-wide concat).
// ---------------------------------------------------------------------------
__global__ __launch_bounds__(512) void gemm_wide_k(
    const void* __restrict__ Ain, const bf16* __restrict__ Bt,
    bf16* __restrict__ Cb, float* __restrict__ Cf, float* __restrict__ Cf2,
    const bf16* __restrict__ bias, int M, int K,
    const int* __restrict__ flag, int drop) {
    __shared__ short sA[128 * 32];
    __shared__ short sB[512 * 32];
    const int tid = threadIdx.x;
    const int lane = tid & 63;
    const int w = tid >> 6;
    const int m0 = blockIdx.x * 128;
    const int wm = (w & 1) * 64;
    const int wn = (w >> 1) * 128;

    f32x4 acc[4][8] = {};

    const int arow = tid >> 2;          // 0..127
    const int acol = (tid & 3) * 8;     // 0/8/16/24
    int grow = m0 + arow;
    if (grow >= M) grow = M - 1;
    const bool xf32 = drop && flag[1];

    for (int kk = 0; kk < K; kk += 32) {
        // B tile: 512 rows x 32 k  (4 passes x 512 threads x 16B)
#pragma unroll
        for (int q = 0; q < 4; ++q)
            gl_lds16(Bt + (size_t)(q * 128 + arow) * K + kk + acol,
                     &sB[q * 4096 + tid * 8]);
        // A tile: 128 rows x 32 k
        if (!drop) {
            gl_lds16((const bf16*)Ain + (size_t)grow * K + kk + acol, &sA[tid * 8]);
        } else {
            unsigned gidx = (unsigned)grow * (unsigned)K + (unsigned)(kk + acol);
            float v[8];
            if (xf32) {
                const f32x4* p = (const f32x4*)Ain;
                f32x4 a = p[gidx >> 2], b = p[(gidx >> 2) + 1];
#pragma unroll
                for (int k2 = 0; k2 < 4; ++k2) { v[k2] = a[k2]; v[4 + k2] = b[k2]; }
            } else {
                short8 u = ((const short8*)Ain)[gidx >> 3];
#pragma unroll
                for (int k2 = 0; k2 < 8; ++k2) v[k2] = bfu((unsigned short)u[k2]);
            }
            short8 o;
#pragma unroll
            for (int k2 = 0; k2 < 8; ++k2) {
                float f = keep_elem(gidx + k2) ? v[k2] * 2.0f : 0.0f;
                o[k2] = (short)f2b(f);
            }
            *(short8*)&sA[tid * 8] = o;
        }
        __syncthreads();

        const int fr = lane & 15;
        const int fk = (lane >> 4) * 8;
        short8 af[4], bfr2[8];
#pragma unroll
        for (int i = 0; i < 4; ++i)
            af[i] = *(const short8*)&sA[(wm + i * 16 + fr) * 32 + fk];
#pragma unroll
        for (int j = 0; j < 8; ++j)
            bfr2[j] = *(const short8*)&sB[(wn + j * 16 + fr) * 32 + fk];
#pragma unroll
        for (int i = 0; i < 4; ++i)
#pragma unroll
            for (int j = 0; j < 8; ++j)
                acc[i][j] = __builtin_amdgcn_mfma_f32_16x16x32_bf16(
                    af[i], bfr2[j], acc[i][j], 0, 0, 0);
        __syncthreads();
    }

    const int crow = (lane >> 4) * 4;
    const int ccol = lane & 15;
    if (Cf) {
        const int side = (wn >= 256) ? 1 : 0;
        float* base = side ? Cf2 : Cf;
        const int nb = wn - side * 256;
#pragma unroll
        for (int i = 0; i < 4; ++i) {
#pragma unroll
            for (int r = 0; r < 4; ++r) {
                int row = m0 + wm + i * 16 + crow + r;
                if (row >= M) continue;
                float* cp = base + (size_t)row * 256 + nb;
#pragma unroll
                for (int j = 0; j < 8; ++j) {
                    int c = j * 16 + ccol;
                    cp[c] = acc[i][j][r] + __bfloat162float(bias[wn + c]);
                }
            }
        }
    } else {
#pragma unroll
        for (int i = 0; i < 4; ++i) {
#pragma unroll
            for (int r = 0; r < 4; ++r) {
                int row = m0 + wm + i * 16 + crow + r;
                if (row >= M) continue;
                bf16* cp = Cb + (size_t)row * 512 + wn;
#pragma unroll
                for (int j = 0; j < 8; ++j)
                    cp[j * 16 + ccol] = __float2bfloat16(acc[i][j][r]);
            }
        }
    }
}

// ---------------------------------------------------------------------------
// CSR gather: out[node] = sum_edges dinv[s]*dinv[node]*t[s] + dinv[node]^2*t[node]
// (+bias, relu if mode==1). One wave per node, lane owns 8 feats (16B loads),
// 8-deep pipeline with next-group col/dinv prefetch.
// ---------------------------------------------------------------------------
__global__ __launch_bounds__(256) void gather_k(
    const bf16* __restrict__ t, const int* __restrict__ row_ptr,
    const int* __restrict__ col, const float* __restrict__ dinv,
    const bf16* __restrict__ bias, bf16* __restrict__ outp, int mode, int N) {
    const int node = blockIdx.x * 4 + (threadIdx.x >> 6);
    if (node >= N) return;
    const int lane = threadIdx.x & 63;
    const short8* tp = (const short8*)t;
    const int beg = row_ptr[node];
    const int end = row_ptr[node + 1];
    const float dv = dinv[node];
    float acc[8] = {0.f, 0.f, 0.f, 0.f, 0.f, 0.f, 0.f, 0.f};

    int e = beg;
    const int elim = beg + ((end - beg) & ~7);
    if (e < elim) {
        int c[8];
        float w[8];
#pragma unroll
        for (int k = 0; k < 8; ++k) c[k] = col[e + k];
#pragma unroll
        for (int k = 0; k < 8; ++k) w[k] = dinv[c[k]] * dv;
        for (;;) {
            short8 u[8];
#pragma unroll
            for (int k = 0; k < 8; ++k) u[k] = tp[(size_t)c[k] * 64 + lane];
            const int en = e + 8;
            const bool more = en < elim;
            int cn[8];
            float wn2[8];
            if (more) {
#pragma unroll
                for (int k = 0; k < 8; ++k) cn[k] = col[en + k];
#pragma unroll
                for (int k = 0; k < 8; ++k) wn2[k] = dinv[cn[k]] * dv;
            }
#pragma unroll
            for (int k = 0; k < 8; ++k) {
                const float wk = w[k];
#pragma unroll
                for (int j = 0; j < 8; ++j)
                    acc[j] += wk * bfu((unsigned short)u[k][j]);
            }
            e = en;
            if (!more) break;
#pragma unroll
            for (int k = 0; k < 8; ++k) { c[k] = cn[k]; w[k] = wn2[k]; }
        }
    }
    for (; e + 4 <= end; e += 4) {
        int s0 = col[e + 0], s1 = col[e + 1], s2 = col[e + 2], s3 = col[e + 3];
        float w0 = dinv[s0] * dv, w1 = dinv[s1] * dv;
        float w2 = dinv[s2] * dv, w3 = dinv[s3] * dv;
        short8 u0 = tp[(size_t)s0 * 64 + lane];
        short8 u1 = tp[(size_t)s1 * 64 + lane];
        short8 u2 = tp[(size_t)s2 * 64 + lane];
        short8 u3 = tp[(size_t)s3 * 64 + lane];
#pragma unroll
        for (int k = 0; k < 8; ++k) {
            acc[k] += w0 * bfu((unsigned short)u0[k]);
            acc[k] += w1 * bfu((unsigned short)u1[k]);
            acc[k] += w2 * bfu((unsigned short)u2[k]);
            acc[k] += w3 * bfu((unsigned short)u3[k]);
        }
    }
    for (; e < end; ++e) {
        int s = col[e];
        float w = dinv[s] * dv;
        short8 u = tp[(size_t)s * 64 + lane];
#pragma unroll
        for (int k = 0; k < 8; ++k) acc[k] += w * bfu((unsigned short)u[k]);
    }
    {   // self loop
        short8 u = tp[(size_t)node * 64 + lane];
        float w = dv * dv;
#pragma unroll
        for (int k = 0; k < 8; ++k) acc[k] += w * bfu((unsigned short)u[k]);
    }
    if (mode == 1) {
        short8 bs = ((const short8*)bias)[lane];
#pragma unroll
        for (int k = 0; k < 8; ++k) {
            acc[k] += bfu((unsigned short)bs[k]);
            acc[k] = fmaxf(acc[k], 0.f);
        }
    }
    short8 o;
#pragma unroll
    for (int k = 0; k < 8; ++k) o[k] = (short)f2b(acc[k]);
    ((short8*)outp)[(size_t)node * 64 + lane] = o;
}

// ---------------------------------------------------------------------------
extern "C" void kernel_launch(void* const* d_in, const int* in_sizes, int n_in,
                              void* d_out, int out_size, void* d_ws, size_t ws_size,
                              hipStream_t stream) {
    const void* xin   = d_in[0];
    const void* ei    = d_in[1];
    const void* W1in  = d_in[2];
    const void* b1in  = d_in[3];
    const void* Wmuin = d_in[4];
    const void* bmuin = d_in[5];
    const void* Wlsin = d_in[6];
    const void* blsin = d_in[7];
    float* out = (float*)d_out;

    const int H    = in_sizes[3];        // 512
    const int DOUT = in_sizes[5];        // 256
    const int DIN  = in_sizes[2] / H;    // 512
    const int N    = in_sizes[0] / DIN;  // 50000
    const int E    = in_sizes[1] / 2;    // 800000
    const int G    = (N + 255) / 256;

    char* ws = (char*)d_ws;
    size_t off = 0;
    auto alloc = [&](size_t bytes) {
        void* p = ws + off;
        off = (off + bytes + 255) & ~(size_t)255;
        return p;
    };
    int*   flag    = (int*)alloc(256);
    int*   edges   = (int*)alloc((size_t)2 * E * 4);
    int*   degcnt  = (int*)alloc((size_t)2 * N * 4);   // degi | cnt (zeroed together)
    int*   degi    = degcnt;
    int*   cnt     = degcnt + N;
    int*   row_ptr = (int*)alloc((size_t)(N + 1) * 4);
    int*   partial = (int*)alloc((size_t)G * 4);
    int*   col     = (int*)alloc((size_t)E * 4);
    float* dinv    = (float*)alloc((size_t)N * 4);
    bf16*  t1      = (bf16*)alloc((size_t)N * H * 2);
    bf16*  g1      = (bf16*)alloc((size_t)N * H * 2);
    bf16*  h1      = (bf16*)alloc((size_t)N * H * 2);
    bf16*  W1t     = (bf16*)alloc((size_t)DIN * H * 2);      // [H, DIN]
    bf16*  Wcat    = (bf16*)alloc((size_t)H * 2 * DOUT * 2); // [2*DOUT, H]: mu rows then ls
    bf16*  b1c     = (bf16*)alloc((size_t)H * 2);
    bf16*  bcat    = (bf16*)alloc((size_t)2 * DOUT * 2);
    if (off > ws_size) return;

    const int twoE = 2 * E;
    hipLaunchKernelGGL(detect_all_k, dim3(3), dim3(256), 0, stream,
                       (const unsigned*)ei, (const unsigned short*)xin,
                       (const unsigned short*)W1in, flag);

    hipLaunchKernelGGL(convert_edges_k, dim3((twoE + 255) / 256), dim3(256), 0, stream,
                       ei, edges, twoE, flag);
    hipLaunchKernelGGL(canon_transpose_k, dim3(DIN / 16, H / 16), dim3(16, 16), 0, stream,
                       W1in, (unsigned short*)W1t, DIN, H, flag, 2);
    hipLaunchKernelGGL(canon_transpose_k, dim3(H / 16, DOUT / 16), dim3(16, 16), 0, stream,
                       Wmuin, (unsigned short*)Wcat, H, DOUT, flag, 2);
    hipLaunchKernelGGL(canon_transpose_k, dim3(H / 16, DOUT / 16), dim3(16, 16), 0, stream,
                       Wlsin, (unsigned short*)(Wcat + (size_t)DOUT * H), H, DOUT, flag, 2);
    hipLaunchKernelGGL(canon_bias_k, dim3((H + 2 * DOUT + 255) / 256), dim3(256), 0, stream,
                       b1in, bmuin, blsin, b1c, bcat, H, DOUT, flag);

    // CSR build
    hipLaunchKernelGGL(zero_int_k, dim3((2 * N + 255) / 256), dim3(256), 0, stream, degcnt, 2 * N);
    hipLaunchKernelGGL(deg_count_k, dim3((E + 255) / 256), dim3(256), 0, stream, edges, degi, E, N);
    hipLaunchKernelGGL(block_sums_k, dim3(G), dim3(256), 0, stream, degi, partial, N);
    hipLaunchKernelGGL(scan_partials_k, dim3(1), dim3(256), 0, stream, partial, G);
    hipLaunchKernelGGL(scan_block_k, dim3(G), dim3(256), 0, stream, degi, partial, row_ptr, dinv, N);
    hipLaunchKernelGGL(fill_k, dim3((E + 255) / 256), dim3(256), 0, stream, edges, row_ptr, cnt, col, E, N);

    // layer 1: t1 = dropout(x) @ W1 (fused canon+dropout); h1 = relu(gather(t1)+b1)
    hipLaunchKernelGGL(gemm_wide_k, dim3((N + 127) / 128), dim3(512), 0, stream,
                       xin, W1t, t1, (float*)nullptr, (float*)nullptr,
                       (const bf16*)nullptr, N, DIN, flag, 1);
    hipLaunchKernelGGL(gather_k, dim3((N + 3) / 4), dim3(256), 0, stream,
                       t1, row_ptr, col, dinv, b1c, h1, 1, N);

    // layer 2: g1 = gather(h1); [mu|logstd] = g1 @ [Wmu|Wls] + [bmu|bls]
    hipLaunchKernelGGL(gather_k, dim3((N + 3) / 4), dim3(256), 0, stream,
                       h1, row_ptr, col, dinv, (const bf16*)nullptr, g1, 0, N);
    hipLaunchKernelGGL(gemm_wide_k, dim3((N + 127) / 128), dim3(512), 0, stream,
                       g1, Wcat, (bf16*)nullptr, out, out + (size_t)N * DOUT,
                       bcat, N, H, flag, 0);
}

// Round 4
// 643.244 us; speedup vs baseline: 1.0388x; 1.0388x over previous
//
#include <hip/hip_runtime.h>
#include <hip/hip_bf16.h>

typedef __hip_bfloat16 bf16;
typedef __attribute__((ext_vector_type(8))) short short8;
typedef __attribute__((ext_vector_type(4))) float f32x4;

__device__ __forceinline__ float bfu(unsigned short b) {
    unsigned u = ((unsigned)b) << 16;
    float f;
    __builtin_memcpy(&f, &u, 4);
    return f;
}
__device__ __forceinline__ unsigned short f2b(float f) {
    return (unsigned short)(__hip_bfloat16_raw(__float2bfloat16(f)).x);
}

// async global->LDS, 16B per lane; lds dest must be wave-uniform base + lane*16.
__device__ __forceinline__ void gl_lds16(const void* g, void* l) {
    __builtin_amdgcn_global_load_lds(
        (const __attribute__((address_space(1))) void*)g,
        (__attribute__((address_space(3))) void*)l, 16, 0, 0);
}

// ---------------------------------------------------------------------------
// Threefry-2x32 (20 rounds), JAX partitionable: keep = top bit of (x0^x1)==0
// ---------------------------------------------------------------------------
__device__ __forceinline__ bool keep_elem(unsigned idx) {
    const unsigned k0 = 0u, k1 = 42u;
    const unsigned k2 = k0 ^ k1 ^ 0x1BD11BDAu;
    unsigned x0 = k0;
    unsigned x1 = idx + k1;
#define TF_QR(R) { x0 += x1; x1 = (x1 << R) | (x1 >> (32 - R)); x1 ^= x0; }
    TF_QR(13) TF_QR(15) TF_QR(26) TF_QR(6)
    x0 += k1; x1 += k2 + 1u;
    TF_QR(17) TF_QR(29) TF_QR(16) TF_QR(24)
    x0 += k2; x1 += k0 + 2u;
    TF_QR(13) TF_QR(15) TF_QR(26) TF_QR(6)
    x0 += k0; x1 += k1 + 3u;
    TF_QR(17) TF_QR(29) TF_QR(16) TF_QR(24)
    x0 += k1; x1 += k2 + 4u;
    TF_QR(13) TF_QR(15) TF_QR(26) TF_QR(6)
    x0 += k2; x1 += k0 + 5u;
#undef TF_QR
    return (((x0 ^ x1) >> 31) & 1u) == 0u;
}

// ---------------------------------------------------------------------------
// Merged dtype detection: flag[0] edges int64?, flag[1] x f32?, flag[2] W f32?
// ---------------------------------------------------------------------------
__global__ void detect_all_k(const unsigned* __restrict__ ei,
                             const unsigned short* __restrict__ x,
                             const unsigned short* __restrict__ w1,
                             int* __restrict__ flag) {
    __shared__ int red[256];
    if (blockIdx.x == 0) {
        unsigned v = 0;
        for (int i = threadIdx.x; i < 2048; i += 256) v |= ei[2 * i + 1];
        red[threadIdx.x] = (int)v;
        __syncthreads();
        for (int s = 128; s > 0; s >>= 1) {
            if (threadIdx.x < s) red[threadIdx.x] |= red[threadIdx.x + s];
            __syncthreads();
        }
        if (threadIdx.x == 0) flag[0] = (red[0] == 0) ? 1 : 0;
    } else {
        const unsigned short* p = (blockIdx.x == 1) ? x : w1;
        int cnt = 0;
        for (int i = threadIdx.x; i < 1024; i += 256) {
            unsigned short b = p[2 * i];
            int e = (b >> 7) & 0xFF;
            if ((b & 0x7FFF) == 0 || (e >= 100 && e < 140)) cnt++;
        }
        red[threadIdx.x] = cnt;
        __syncthreads();
        for (int s = 128; s > 0; s >>= 1) {
            if (threadIdx.x < s) red[threadIdx.x] += red[threadIdx.x + s];
            __syncthreads();
        }
        if (threadIdx.x == 0) flag[blockIdx.x] = (red[0] < 614) ? 1 : 0;
    }
}

__global__ void convert_edges_k(const void* __restrict__ src, int* __restrict__ out,
                                int twoE, const int* __restrict__ flag) {
    int i = blockIdx.x * 256 + threadIdx.x;
    if (i >= twoE) return;
    if (flag[0]) out[i] = (int)((const unsigned long long*)src)[i];
    else         out[i] = ((const int*)src)[i];
}

// canonicalize + transpose weight [K,Nn] -> [Nn,K] (both multiples of 16)
__global__ void canon_transpose_k(const void* __restrict__ src, unsigned short* __restrict__ dst,
                                  int K, int Nn, const int* __restrict__ flag, int fidx) {
    __shared__ unsigned short tile[16][17];
    int k0 = blockIdx.x * 16, n0 = blockIdx.y * 16;
    int k = k0 + threadIdx.y, n = n0 + threadIdx.x;
    unsigned short v;
    if (flag[fidx]) v = f2b(((const float*)src)[(size_t)k * Nn + n]);
    else            v = ((const unsigned short*)src)[(size_t)k * Nn + n];
    tile[threadIdx.y][threadIdx.x] = v;
    __syncthreads();
    int nn = n0 + threadIdx.y, kk = k0 + threadIdx.x;
    dst[(size_t)nn * K + kk] = tile[threadIdx.x][threadIdx.y];
}

// merged bias canon: b1c[0..H) from b1, bcat[0..DOUT) from bmu, [DOUT..2*DOUT) from bls
__global__ void canon_bias_k(const void* __restrict__ b1, const void* __restrict__ bmu,
                             const void* __restrict__ bls, bf16* __restrict__ b1c,
                             bf16* __restrict__ bcat, int H, int DOUT,
                             const int* __restrict__ flag) {
    int i = blockIdx.x * 256 + threadIdx.x;
    int f = flag[2];
    if (i < H) {
        b1c[i] = f ? __float2bfloat16(((const float*)b1)[i]) : ((const bf16*)b1)[i];
    } else if (i < H + DOUT) {
        int j = i - H;
        bcat[j] = f ? __float2bfloat16(((const float*)bmu)[j]) : ((const bf16*)bmu)[j];
    } else if (i < H + 2 * DOUT) {
        int j = i - H - DOUT;
        bcat[DOUT + j] = f ? __float2bfloat16(((const float*)bls)[j]) : ((const bf16*)bls)[j];
    }
}

// ---------------------------------------------------------------------------
// CSR build
// ---------------------------------------------------------------------------
__global__ void zero_int_k(int* __restrict__ p, int n) {
    int i = blockIdx.x * 256 + threadIdx.x;
    if (i < n) p[i] = 0;
}
__global__ void deg_count_k(const int* __restrict__ edges, int* __restrict__ degi,
                            int E, int n) {
    int e = blockIdx.x * 256 + threadIdx.x;
    if (e >= E) return;
    int d = edges[E + e];
    d = (d < 0) ? 0 : (d >= n ? n - 1 : d);
    atomicAdd(&degi[d], 1);
}
__global__ void block_sums_k(const int* __restrict__ deg, int* __restrict__ partial, int n) {
    __shared__ int sh[256];
    int i = blockIdx.x * 256 + threadIdx.x;
    sh[threadIdx.x] = (i < n) ? deg[i] : 0;
    __syncthreads();
    for (int s = 128; s > 0; s >>= 1) {
        if (threadIdx.x < s) sh[threadIdx.x] += sh[threadIdx.x + s];
        __syncthreads();
    }
    if (threadIdx.x == 0) partial[blockIdx.x] = sh[0];
}
__global__ void scan_partials_k(int* __restrict__ partial, int G) {
    __shared__ int sh[256];
    int v = (threadIdx.x < G) ? partial[threadIdx.x] : 0;
    sh[threadIdx.x] = v;
    __syncthreads();
    for (int s = 1; s < 256; s <<= 1) {
        int t = 0;
        if (threadIdx.x >= s) t = sh[threadIdx.x - s];
        __syncthreads();
        sh[threadIdx.x] += t;
        __syncthreads();
    }
    if (threadIdx.x < G) partial[threadIdx.x] = sh[threadIdx.x] - v;
}
// scan + dinv fused (dinv[i] = rsqrt(1+deg[i]))
__global__ void scan_block_k(const int* __restrict__ deg, const int* __restrict__ partial,
                             int* __restrict__ row_ptr, float* __restrict__ dinv, int n) {
    __shared__ int sh[256];
    int i = blockIdx.x * 256 + threadIdx.x;
    int v = (i < n) ? deg[i] : 0;
    sh[threadIdx.x] = v;
    __syncthreads();
    for (int s = 1; s < 256; s <<= 1) {
        int t = 0;
        if (threadIdx.x >= s) t = sh[threadIdx.x - s];
        __syncthreads();
        sh[threadIdx.x] += t;
        __syncthreads();
    }
    int incl = sh[threadIdx.x];
    int base = partial[blockIdx.x];
    if (i < n) {
        row_ptr[i] = base + incl - v;
        dinv[i] = rsqrtf(1.0f + (float)v);
    }
    if (i == n - 1) row_ptr[n] = base + incl;
}
__global__ void fill_k(const int* __restrict__ edges, const int* __restrict__ row_ptr,
                       int* __restrict__ cnt, int* __restrict__ col, int E, int n) {
    int e = blockIdx.x * 256 + threadIdx.x;
    if (e >= E) return;
    int s = edges[e], d = edges[E + e];
    s = (s < 0) ? 0 : (s >= n ? n - 1 : s);
    d = (d < 0) ? 0 : (d >= n ? n - 1 : d);
    int pos = row_ptr[d] + atomicAdd(&cnt[d], 1);
    col[pos] = s;
}

// ---------------------------------------------------------------------------
// Wide-N MFMA GEMM: C[M,512] = A[M,K] @ Bt[512,K]^T, BM=128, BN=512, BK=64.
// 8 waves (2M x 4N), each wave 64x128 tile = 4x8 of 16x16x32 bf16 MFMA x2 k-slices.
// LDS rows are 128B (64 shorts); 16B slots XOR-swizzled: slot ^= (row&7), so the
// 16-lane fragment reads (rows 128B apart, same slot) spread over all 32 banks
// (2-way alias only = free). global_load_lds keeps a LINEAR dest; the swizzle is
// applied by permuting the per-lane GLOBAL source k-chunk (m104/m201 pattern).
// drop=1: A staged via regs from x (f32/bf16 per flag[1]) + fused threefry
//         dropout (idx = row*K + k, matches reference mask; hashed exactly once).
// Epilogue: Cb!=null -> bf16 [M,512]; else f32 split: cols<256 -> Cf,
//           cols>=256 -> Cf2 (row stride 256), + bf16 bias (512-wide concat).
// ---------------------------------------------------------------------------
__global__ __launch_bounds__(512) void gemm_wide_k(
    const void* __restrict__ Ain, const bf16* __restrict__ Bt,
    bf16* __restrict__ Cb, float* __restrict__ Cf, float* __restrict__ Cf2,
    const bf16* __restrict__ bias, int M, int K,
    const int* __restrict__ flag, int drop) {
    __shared__ short sA[128 * 64];   // 16 KB
    __shared__ short sB[512 * 64];   // 64 KB
    const int tid = threadIdx.x;
    const int lane = tid & 63;
    const int w = tid >> 6;
    const int m0 = blockIdx.x * 128;
    const int wm = (w & 1) * 64;
    const int wn = (w >> 1) * 128;

    f32x4 acc[4][8] = {};

    // staging geometry: dest (row-in-pass, slot) = (tid>>3, tid&7); the data for
    // dest slot s of row r is global k-chunk s ^ (r&7).
    const int srow = tid >> 3;                       // 0..63 within a 64-row pass
    const int schunk = (tid & 7) ^ (srow & 7);       // global 16B k-chunk to fetch
    const int scol = schunk * 8;                     // shorts
    const bool xf32 = drop && flag[1];

    for (int kk = 0; kk < K; kk += 64) {
        // B tile: 512 rows x 64k, 8 passes of 512 threads x 16B
#pragma unroll
        for (int p = 0; p < 8; ++p)
            gl_lds16(Bt + (size_t)(p * 64 + srow) * K + kk + scol,
                     &sB[p * 4096 + tid * 8]);
        // A tile: 128 rows x 64k, 2 passes
        if (!drop) {
#pragma unroll
            for (int p = 0; p < 2; ++p) {
                int r = m0 + p * 64 + srow; if (r >= M) r = M - 1;
                gl_lds16((const bf16*)Ain + (size_t)r * K + kk + scol,
                         &sA[p * 4096 + tid * 8]);
            }
        } else {
#pragma unroll
            for (int p = 0; p < 2; ++p) {
                int r = m0 + p * 64 + srow; if (r >= M) r = M - 1;
                unsigned gidx = (unsigned)r * (unsigned)K + (unsigned)(kk + scol);
                float v[8];
                if (xf32) {
                    const f32x4* pp = (const f32x4*)Ain;
                    f32x4 a = pp[gidx >> 2], b = pp[(gidx >> 2) + 1];
#pragma unroll
                    for (int k2 = 0; k2 < 4; ++k2) { v[k2] = a[k2]; v[4 + k2] = b[k2]; }
                } else {
                    short8 u = ((const short8*)Ain)[gidx >> 3];
#pragma unroll
                    for (int k2 = 0; k2 < 8; ++k2) v[k2] = bfu((unsigned short)u[k2]);
                }
                short8 o;
#pragma unroll
                for (int k2 = 0; k2 < 8; ++k2) {
                    float f = keep_elem(gidx + k2) ? v[k2] * 2.0f : 0.0f;
                    o[k2] = (short)f2b(f);
                }
                *(short8*)&sA[p * 4096 + tid * 8] = o;  // linear write, conflict-free
            }
        }
        __syncthreads();

        const int fr = lane & 15;
        const int q = lane >> 4;         // 16B slot quarter within k-slice
#pragma unroll
        for (int ks = 0; ks < 2; ++ks) {
            const int slot = ks * 4 + q;
            short8 af[4], bf2[8];
#pragma unroll
            for (int i = 0; i < 4; ++i) {
                int r = wm + i * 16 + fr;
                af[i] = *(const short8*)&sA[r * 64 + ((slot ^ (r & 7)) * 8)];
            }
#pragma unroll
            for (int j = 0; j < 8; ++j) {
                int r = wn + j * 16 + fr;
                bf2[j] = *(const short8*)&sB[r * 64 + ((slot ^ (r & 7)) * 8)];
            }
#pragma unroll
            for (int i = 0; i < 4; ++i)
#pragma unroll
                for (int j = 0; j < 8; ++j)
                    acc[i][j] = __builtin_amdgcn_mfma_f32_16x16x32_bf16(
                        af[i], bf2[j], acc[i][j], 0, 0, 0);
        }
        __syncthreads();
    }

    const int crow = (lane >> 4) * 4;
    const int ccol = lane & 15;
    if (Cf) {
        const int side = (wn >= 256) ? 1 : 0;
        float* base = side ? Cf2 : Cf;
        const int nb = wn - side * 256;
#pragma unroll
        for (int i = 0; i < 4; ++i) {
#pragma unroll
            for (int r = 0; r < 4; ++r) {
                int row = m0 + wm + i * 16 + crow + r;
                if (row >= M) continue;
                float* cp = base + (size_t)row * 256 + nb;
#pragma unroll
                for (int j = 0; j < 8; ++j) {
                    int c = j * 16 + ccol;
                    cp[c] = acc[i][j][r] + __bfloat162float(bias[wn + c]);
                }
            }
        }
    } else {
#pragma unroll
        for (int i = 0; i < 4; ++i) {
#pragma unroll
            for (int r = 0; r < 4; ++r) {
                int row = m0 + wm + i * 16 + crow + r;
                if (row >= M) continue;
                bf16* cp = Cb + (size_t)row * 512 + wn;
#pragma unroll
                for (int j = 0; j < 8; ++j)
                    cp[j * 16 + ccol] = __float2bfloat16(acc[i][j][r]);
            }
        }
    }
}

// ---------------------------------------------------------------------------
// CSR gather: out[node] = sum_edges dinv[s]*dinv[node]*t[s] + dinv[node]^2*t[node]
// (+bias, relu if mode==1). One wave per node, lane owns 8 feats (16B loads),
// 8-deep pipeline with next-group col/dinv prefetch. (At its access-pattern
// ceiling per rounds 1-2: ~7 TB/s L2-level delivery.)
// ---------------------------------------------------------------------------
__global__ __launch_bounds__(256) void gather_k(
    const bf16* __restrict__ t, const int* __restrict__ row_ptr,
    const int* __restrict__ col, const float* __restrict__ dinv,
    const bf16* __restrict__ bias, bf16* __restrict__ outp, int mode, int N) {
    const int node = blockIdx.x * 4 + (threadIdx.x >> 6);
    if (node >= N) return;
    const int lane = threadIdx.x & 63;
    const short8* tp = (const short8*)t;
    const int beg = row_ptr[node];
    const int end = row_ptr[node + 1];
    const float dv = dinv[node];
    float acc[8] = {0.f, 0.f, 0.f, 0.f, 0.f, 0.f, 0.f, 0.f};

    int e = beg;
    const int elim = beg + ((end - beg) & ~7);
    if (e < elim) {
        int c[8];
        float w[8];
#pragma unroll
        for (int k = 0; k < 8; ++k) c[k] = col[e + k];
#pragma unroll
        for (int k = 0; k < 8; ++k) w[k] = dinv[c[k]] * dv;
        for (;;) {
            short8 u[8];
#pragma unroll
            for (int k = 0; k < 8; ++k) u[k] = tp[(size_t)c[k] * 64 + lane];
            const int en = e + 8;
            const bool more = en < elim;
            int cn[8];
            float wn2[8];
            if (more) {
#pragma unroll
                for (int k = 0; k < 8; ++k) cn[k] = col[en + k];
#pragma unroll
                for (int k = 0; k < 8; ++k) wn2[k] = dinv[cn[k]] * dv;
            }
#pragma unroll
            for (int k = 0; k < 8; ++k) {
                const float wk = w[k];
#pragma unroll
                for (int j = 0; j < 8; ++j)
                    acc[j] += wk * bfu((unsigned short)u[k][j]);
            }
            e = en;
            if (!more) break;
#pragma unroll
            for (int k = 0; k < 8; ++k) { c[k] = cn[k]; w[k] = wn2[k]; }
        }
    }
    for (; e + 4 <= end; e += 4) {
        int s0 = col[e + 0], s1 = col[e + 1], s2 = col[e + 2], s3 = col[e + 3];
        float w0 = dinv[s0] * dv, w1 = dinv[s1] * dv;
        float w2 = dinv[s2] * dv, w3 = dinv[s3] * dv;
        short8 u0 = tp[(size_t)s0 * 64 + lane];
        short8 u1 = tp[(size_t)s1 * 64 + lane];
        short8 u2 = tp[(size_t)s2 * 64 + lane];
        short8 u3 = tp[(size_t)s3 * 64 + lane];
#pragma unroll
        for (int k = 0; k < 8; ++k) {
            acc[k] += w0 * bfu((unsigned short)u0[k]);
            acc[k] += w1 * bfu((unsigned short)u1[k]);
            acc[k] += w2 * bfu((unsigned short)u2[k]);
            acc[k] += w3 * bfu((unsigned short)u3[k]);
        }
    }
    for (; e < end; ++e) {
        int s = col[e];
        float w = dinv[s] * dv;
        short8 u = tp[(size_t)s * 64 + lane];
#pragma unroll
        for (int k = 0; k < 8; ++k) acc[k] += w * bfu((unsigned short)u[k]);
    }
    {   // self loop
        short8 u = tp[(size_t)node * 64 + lane];
        float w = dv * dv;
#pragma unroll
        for (int k = 0; k < 8; ++k) acc[k] += w * bfu((unsigned short)u[k]);
    }
    if (mode == 1) {
        short8 bs = ((const short8*)bias)[lane];
#pragma unroll
        for (int k = 0; k < 8; ++k) {
            acc[k] += bfu((unsigned short)bs[k]);
            acc[k] = fmaxf(acc[k], 0.f);
        }
    }
    short8 o;
#pragma unroll
    for (int k = 0; k < 8; ++k) o[k] = (short)f2b(acc[k]);
    ((short8*)outp)[(size_t)node * 64 + lane] = o;
}

// ---------------------------------------------------------------------------
extern "C" void kernel_launch(void* const* d_in, const int* in_sizes, int n_in,
                              void* d_out, int out_size, void* d_ws, size_t ws_size,
                              hipStream_t stream) {
    const void* xin   = d_in[0];
    const void* ei    = d_in[1];
    const void* W1in  = d_in[2];
    const void* b1in  = d_in[3];
    const void* Wmuin = d_in[4];
    const void* bmuin = d_in[5];
    const void* Wlsin = d_in[6];
    const void* blsin = d_in[7];
    float* out = (float*)d_out;

    const int H    = in_sizes[3];        // 512
    const int DOUT = in_sizes[5];        // 256
    const int DIN  = in_sizes[2] / H;    // 512
    const int N    = in_sizes[0] / DIN;  // 50000
    const int E    = in_sizes[1] / 2;    // 800000
    const int G    = (N + 255) / 256;

    char* ws = (char*)d_ws;
    size_t off = 0;
    auto alloc = [&](size_t bytes) {
        void* p = ws + off;
        off = (off + bytes + 255) & ~(size_t)255;
        return p;
    };
    int*   flag    = (int*)alloc(256);
    int*   edges   = (int*)alloc((size_t)2 * E * 4);
    int*   degcnt  = (int*)alloc((size_t)2 * N * 4);   // degi | cnt (zeroed together)
    int*   degi    = degcnt;
    int*   cnt     = degcnt + N;
    int*   row_ptr = (int*)alloc((size_t)(N + 1) * 4);
    int*   partial = (int*)alloc((size_t)G * 4);
    int*   col     = (int*)alloc((size_t)E * 4);
    float* dinv    = (float*)alloc((size_t)N * 4);
    bf16*  t1      = (bf16*)alloc((size_t)N * H * 2);
    bf16*  g1      = (bf16*)alloc((size_t)N * H * 2);
    bf16*  h1      = (bf16*)alloc((size_t)N * H * 2);
    bf16*  W1t     = (bf16*)alloc((size_t)DIN * H * 2);      // [H, DIN]
    bf16*  Wcat    = (bf16*)alloc((size_t)H * 2 * DOUT * 2); // [2*DOUT, H]: mu rows then ls
    bf16*  b1c     = (bf16*)alloc((size_t)H * 2);
    bf16*  bcat    = (bf16*)alloc((size_t)2 * DOUT * 2);
    if (off > ws_size) return;

    const int twoE = 2 * E;
    hipLaunchKernelGGL(detect_all_k, dim3(3), dim3(256), 0, stream,
                       (const unsigned*)ei, (const unsigned short*)xin,
                       (const unsigned short*)W1in, flag);

    hipLaunchKernelGGL(convert_edges_k, dim3((twoE + 255) / 256), dim3(256), 0, stream,
                       ei, edges, twoE, flag);
    hipLaunchKernelGGL(canon_transpose_k, dim3(DIN / 16, H / 16), dim3(16, 16), 0, stream,
                       W1in, (unsigned short*)W1t, DIN, H, flag, 2);
    hipLaunchKernelGGL(canon_transpose_k, dim3(H / 16, DOUT / 16), dim3(16, 16), 0, stream,
                       Wmuin, (unsigned short*)Wcat, H, DOUT, flag, 2);
    hipLaunchKernelGGL(canon_transpose_k, dim3(H / 16, DOUT / 16), dim3(16, 16), 0, stream,
                       Wlsin, (unsigned short*)(Wcat + (size_t)DOUT * H), H, DOUT, flag, 2);
    hipLaunchKernelGGL(canon_bias_k, dim3((H + 2 * DOUT + 255) / 256), dim3(256), 0, stream,
                       b1in, bmuin, blsin, b1c, bcat, H, DOUT, flag);

    // CSR build
    hipLaunchKernelGGL(zero_int_k, dim3((2 * N + 255) / 256), dim3(256), 0, stream, degcnt, 2 * N);
    hipLaunchKernelGGL(deg_count_k, dim3((E + 255) / 256), dim3(256), 0, stream, edges, degi, E, N);
    hipLaunchKernelGGL(block_sums_k, dim3(G), dim3(256), 0, stream, degi, partial, N);
    hipLaunchKernelGGL(scan_partials_k, dim3(1), dim3(256), 0, stream, partial, G);
    hipLaunchKernelGGL(scan_block_k, dim3(G), dim3(256), 0, stream, degi, partial, row_ptr, dinv, N);
    hipLaunchKernelGGL(fill_k, dim3((E + 255) / 256), dim3(256), 0, stream, edges, row_ptr, cnt, col, E, N);

    // layer 1: t1 = dropout(x) @ W1 (fused canon+dropout); h1 = relu(gather(t1)+b1)
    hipLaunchKernelGGL(gemm_wide_k, dim3((N + 127) / 128), dim3(512), 0, stream,
                       xin, W1t, t1, (float*)nullptr, (float*)nullptr,
                       (const bf16*)nullptr, N, DIN, flag, 1);
    hipLaunchKernelGGL(gather_k, dim3((N + 3) / 4), dim3(256), 0, stream,
                       t1, row_ptr, col, dinv, b1c, h1, 1, N);

    // layer 2: g1 = gather(h1); [mu|logstd] = g1 @ [Wmu|Wls] + [bmu|bls]
    hipLaunchKernelGGL(gather_k, dim3((N + 3) / 4), dim3(256), 0, stream,
                       h1, row_ptr, col, dinv, (const bf16*)nullptr, g1, 0, N);
    hipLaunchKernelGGL(gemm_wide_k, dim3((N + 127) / 128), dim3(512), 0, stream,
                       g1, Wcat, (bf16*)nullptr, out, out + (size_t)N * DOUT,
                       bcat, N, H, flag, 0);
}